// Round 8
// baseline (125.056 us; speedup 1.0000x reference)
//
#include <hip/hip_runtime.h>

// RenderMeshColor: B=16, P=100000, F=200000
// Two-phase: (1) transform each point once -> 32B record in ws,
//            (2) gather 3 records/face (1 line each), normals, flush.

constexpr int Bn = 16;
constexpr int Pn = 100000;
constexpr int Fn = 200000;
constexpr int ChunksPerB = (Fn + 255) / 256;   // 782

constexpr size_t O0 = 0;
constexpr size_t O1 = (size_t)Bn * Fn * 9;
constexpr size_t O2 = O1 + (size_t)Bn * Fn * 6;
constexpr size_t O3 = O2 + (size_t)Bn * Fn * 1;
constexpr size_t O4 = O3 + (size_t)Bn * Fn * 9;

constexpr size_t REC_BYTES = (size_t)Bn * Pn * 8 * sizeof(float);  // 51.2 MB

typedef float floatx4 __attribute__((ext_vector_type(4)));

struct V3 { float x, y, z; };

// BLAS-order 3-term dot: c = fma(a2,b2, fma(a1,b1, rn(a0*b0)))
__device__ __forceinline__ float dot3_blas(float a0, float a1, float a2,
                                           float b0, float b1, float b2) {
    return fmaf(a2, b2, fmaf(a1, b1, __fmul_rn(a0, b0)));
}

// Coalesced LDS->global flush: lane-contiguous float4 stores.
__device__ __forceinline__ void flush4(float* __restrict__ dst,
                                       const float* __restrict__ src,
                                       int nfloats, int tid) {
    const floatx4* s4 = (const floatx4*)src;
    floatx4* d4 = (floatx4*)dst;
    const int n4 = nfloats >> 2;
    for (int i = tid; i < n4; i += 256) d4[i] = s4[i];
}

// ---------------- Phase 1: per-(b,p) transform -> 32B record -----------------
// rec[b][p] = {tx,ty,tz,xy0, xy1,cr,cg,cb}  (two float4s)
__global__ __launch_bounds__(256)
void transform_kernel(const float* __restrict__ points,    // [B,P,3]
                      const float* __restrict__ tfcolor,   // [B,P,3]
                      const float* __restrict__ cam_rot,   // [B,3,3]
                      const float* __restrict__ cam_pos,   // [B,3]
                      const float* __restrict__ cam_proj,  // [3]
                      floatx4* __restrict__ rec)
{
    const int p = blockIdx.x * 256 + threadIdx.x;
    const int b = blockIdx.y;
    if (p >= Pn) return;

    const float r00 = cam_rot[b * 9 + 0], r01 = cam_rot[b * 9 + 1], r02 = cam_rot[b * 9 + 2];
    const float r10 = cam_rot[b * 9 + 3], r11 = cam_rot[b * 9 + 4], r12 = cam_rot[b * 9 + 5];
    const float r20 = cam_rot[b * 9 + 6], r21 = cam_rot[b * 9 + 7], r22 = cam_rot[b * 9 + 8];
    const float cp0 = cam_pos[b * 3 + 0], cp1 = cam_pos[b * 3 + 1], cp2 = cam_pos[b * 3 + 2];
    const float pj0 = cam_proj[0], pj1 = cam_proj[1], pj2 = cam_proj[2];

    const V3 pt = ((const V3*)(points  + (size_t)b * Pn * 3))[p];
    const V3 cl = ((const V3*)(tfcolor + (size_t)b * Pn * 3))[p];

    // Bit-identical to the previously passing per-face math.
    const float dx = __fsub_rn(pt.x, cp0);
    const float dy = __fsub_rn(pt.y, cp1);
    const float dz = __fsub_rn(pt.z, cp2);
    const float tx = dot3_blas(dx, dy, dz, r00, r01, r02);
    const float ty = dot3_blas(dx, dy, dz, r10, r11, r12);
    const float tz = dot3_blas(dx, dy, dz, r20, r21, r22);
    const float zv = __fmul_rn(tz, pj2);
    const float x0 = __fdiv_rn(__fmul_rn(tx, pj0), zv);
    const float x1 = __fdiv_rn(__fmul_rn(ty, pj1), zv);

    floatx4 ra = {tx, ty, tz, x0};
    floatx4 rb = {x1, cl.x, cl.y, cl.z};
    floatx4* r4 = rec + ((size_t)b * Pn + p) * 2;
    r4[0] = ra;
    r4[1] = rb;
}

// ---------------- Phase 2: per-(b,f) gather records, normals, flush ----------
__global__ __launch_bounds__(256)
void face_kernel(const int* __restrict__ faces,        // [F,3]
                 const floatx4* __restrict__ rec,      // [B,P,2] float4
                 float* __restrict__ out)
{
    __shared__ __align__(16) float s3d[256 * 9];
    __shared__ __align__(16) float s2d[256 * 6];
    __shared__ __align__(16) float snz[256];
    __shared__ __align__(16) float scl[256 * 9];
    __shared__ __align__(16) float sn1[256 * 3];

    // XCD-aware batch grouping (XCD k -> batches {k, k+8}).
    const int blid = blockIdx.x;
    const int xcd  = blid & 7;
    const int s    = blid >> 3;
    const int b    = xcd + 8 * (s / ChunksPerB);
    const int blockStart = (s % ChunksPerB) * 256;

    const int t = threadIdx.x;
    const int f = blockStart + t;
    const int nvalid = min(256, Fn - blockStart);

    if (f < Fn) {
        const int i0 = faces[f * 3 + 0];
        const int i1 = faces[f * 3 + 1];
        const int i2 = faces[f * 3 + 2];
        const int idxs[3] = {i0, i1, i2};

        const floatx4* rb4 = rec + (size_t)b * Pn * 2;

        float px[3][3];
#pragma unroll
        for (int v = 0; v < 3; ++v) {
            const size_t base = (size_t)idxs[v] * 2;
            const floatx4 va = rb4[base + 0];   // {tx,ty,tz,xy0} — one line
            const floatx4 vb = rb4[base + 1];   // {xy1,cr,cg,cb} — same line
            px[v][0] = va.x; px[v][1] = va.y; px[v][2] = va.z;
            s3d[t * 9 + v * 3 + 0] = va.x;
            s3d[t * 9 + v * 3 + 1] = va.y;
            s3d[t * 9 + v * 3 + 2] = va.z;
            s2d[t * 6 + v * 2 + 0] = va.w;
            s2d[t * 6 + v * 2 + 1] = vb.x;
            scl[t * 9 + v * 3 + 0] = vb.y;
            scl[t * 9 + v * 3 + 1] = vb.z;
            scl[t * 9 + v * 3 + 2] = vb.w;
        }

        // normal = cross(p1-p0, p2-p0)
        const float e1x = px[1][0] - px[0][0], e1y = px[1][1] - px[0][1], e1z = px[1][2] - px[0][2];
        const float e2x = px[2][0] - px[0][0], e2y = px[2][1] - px[0][1], e2z = px[2][2] - px[0][2];
        const float nx = e1y * e2z - e1z * e2y;
        const float ny = e1z * e2x - e1x * e2z;
        const float nz = e1x * e2y - e1y * e2x;
        const float len = sqrtf(nx * nx + ny * ny + nz * nz);
        const float inv = 1.0f / (len + 1e-15f);

        snz[t] = nz;
        sn1[t * 3 + 0] = nx * inv;
        sn1[t * 3 + 1] = ny * inv;
        sn1[t * 3 + 2] = nz * inv;
    }

    __syncthreads();

    const size_t bf0 = (size_t)b * Fn + blockStart;
    flush4(out + O0 + bf0 * 9, s3d, nvalid * 9, t);
    flush4(out + O1 + bf0 * 6, s2d, nvalid * 6, t);
    flush4(out + O2 + bf0 * 1, snz, nvalid * 1, t);
    flush4(out + O3 + bf0 * 9, scl, nvalid * 9, t);
    flush4(out + O4 + bf0 * 3, sn1, nvalid * 3, t);
}

// ---------------- Fallback (ws too small): R6 monolithic kernel --------------
__global__ __launch_bounds__(256)
void render_mesh_fallback(const float* __restrict__ points,
                          const float* __restrict__ tfcolor,
                          const int*   __restrict__ faces,
                          const float* __restrict__ cam_rot,
                          const float* __restrict__ cam_pos,
                          const float* __restrict__ cam_proj,
                          float* __restrict__ out)
{
    __shared__ __align__(16) float s3d[256 * 9];
    __shared__ __align__(16) float s2d[256 * 6];
    __shared__ __align__(16) float snz[256];
    __shared__ __align__(16) float scl[256 * 9];
    __shared__ __align__(16) float sn1[256 * 3];

    const int blid = blockIdx.x;
    const int xcd  = blid & 7;
    const int s    = blid >> 3;
    const int b    = xcd + 8 * (s / ChunksPerB);
    const int blockStart = (s % ChunksPerB) * 256;

    const int t = threadIdx.x;
    const int f = blockStart + t;
    const int nvalid = min(256, Fn - blockStart);

    if (f < Fn) {
        const float r00 = cam_rot[b * 9 + 0], r01 = cam_rot[b * 9 + 1], r02 = cam_rot[b * 9 + 2];
        const float r10 = cam_rot[b * 9 + 3], r11 = cam_rot[b * 9 + 4], r12 = cam_rot[b * 9 + 5];
        const float r20 = cam_rot[b * 9 + 6], r21 = cam_rot[b * 9 + 7], r22 = cam_rot[b * 9 + 8];
        const float cp0 = cam_pos[b * 3 + 0], cp1 = cam_pos[b * 3 + 1], cp2 = cam_pos[b * 3 + 2];
        const float pj0 = cam_proj[0], pj1 = cam_proj[1], pj2 = cam_proj[2];

        const int i0 = faces[f * 3 + 0];
        const int i1 = faces[f * 3 + 1];
        const int i2 = faces[f * 3 + 2];
        const int idxs[3] = {i0, i1, i2};

        const V3* pb = (const V3*)(points  + (size_t)b * Pn * 3);
        const V3* cb = (const V3*)(tfcolor + (size_t)b * Pn * 3);

        float px[3][3];
#pragma unroll
        for (int v = 0; v < 3; ++v) {
            const int id = idxs[v];
            const V3 p = pb[id];
            const V3 c = cb[id];
            const float dx = __fsub_rn(p.x, cp0);
            const float dy = __fsub_rn(p.y, cp1);
            const float dz = __fsub_rn(p.z, cp2);
            const float tx = dot3_blas(dx, dy, dz, r00, r01, r02);
            const float ty = dot3_blas(dx, dy, dz, r10, r11, r12);
            const float tz = dot3_blas(dx, dy, dz, r20, r21, r22);
            px[v][0] = tx; px[v][1] = ty; px[v][2] = tz;
            s3d[t * 9 + v * 3 + 0] = tx;
            s3d[t * 9 + v * 3 + 1] = ty;
            s3d[t * 9 + v * 3 + 2] = tz;
            const float zv = __fmul_rn(tz, pj2);
            s2d[t * 6 + v * 2 + 0] = __fdiv_rn(__fmul_rn(tx, pj0), zv);
            s2d[t * 6 + v * 2 + 1] = __fdiv_rn(__fmul_rn(ty, pj1), zv);
            scl[t * 9 + v * 3 + 0] = c.x;
            scl[t * 9 + v * 3 + 1] = c.y;
            scl[t * 9 + v * 3 + 2] = c.z;
        }

        const float e1x = px[1][0] - px[0][0], e1y = px[1][1] - px[0][1], e1z = px[1][2] - px[0][2];
        const float e2x = px[2][0] - px[0][0], e2y = px[2][1] - px[0][1], e2z = px[2][2] - px[0][2];
        const float nx = e1y * e2z - e1z * e2y;
        const float ny = e1z * e2x - e1x * e2z;
        const float nz = e1x * e2y - e1y * e2x;
        const float len = sqrtf(nx * nx + ny * ny + nz * nz);
        const float inv = 1.0f / (len + 1e-15f);

        snz[t] = nz;
        sn1[t * 3 + 0] = nx * inv;
        sn1[t * 3 + 1] = ny * inv;
        sn1[t * 3 + 2] = nz * inv;
    }

    __syncthreads();

    const size_t bf0 = (size_t)b * Fn + blockStart;
    flush4(out + O0 + bf0 * 9, s3d, nvalid * 9, t);
    flush4(out + O1 + bf0 * 6, s2d, nvalid * 6, t);
    flush4(out + O2 + bf0 * 1, snz, nvalid * 1, t);
    flush4(out + O3 + bf0 * 9, scl, nvalid * 9, t);
    flush4(out + O4 + bf0 * 3, sn1, nvalid * 3, t);
}

extern "C" void kernel_launch(void* const* d_in, const int* in_sizes, int n_in,
                              void* d_out, int out_size, void* d_ws, size_t ws_size,
                              hipStream_t stream) {
    const float* points   = (const float*)d_in[0];
    const float* tfcolor  = (const float*)d_in[1];
    const int*   faces    = (const int*)d_in[2];
    const float* cam_rot  = (const float*)d_in[3];
    const float* cam_pos  = (const float*)d_in[4];
    const float* cam_proj = (const float*)d_in[5];
    float* out = (float*)d_out;

    if (ws_size >= REC_BYTES) {
        floatx4* rec = (floatx4*)d_ws;
        dim3 g1((Pn + 255) / 256, Bn);
        transform_kernel<<<g1, 256, 0, stream>>>(points, tfcolor, cam_rot,
                                                 cam_pos, cam_proj, rec);
        dim3 g2(Bn * ChunksPerB);
        face_kernel<<<g2, 256, 0, stream>>>(faces, rec, out);
    } else {
        dim3 grid(Bn * ChunksPerB);
        render_mesh_fallback<<<grid, 256, 0, stream>>>(points, tfcolor, faces,
                                                       cam_rot, cam_pos, cam_proj, out);
    }
}

// Round 9
// 103.147 us; speedup vs baseline: 1.2124x; 1.2124x over previous
//
#include <hip/hip_runtime.h>

// RenderMeshColor: B=16, P=100000, F=200000
// R9 = R7 monolithic kernel + nontemporal flush stores (ONLY change).
// Outputs (concatenated flat, float32):
//   points3d_bxfx9   [16,200000,9]
//   points2d_bxfx6   [16,200000,6]
//   normalz_bxfx1    [16,200000,1]
//   tfcolor_bxfx9    [16,200000,9]
//   normal1_bxfx3    [16,200000,3]

constexpr int Bn = 16;
constexpr int Pn = 100000;
constexpr int Fn = 200000;
constexpr int ChunksPerB = (Fn + 255) / 256;   // 782

constexpr size_t O0 = 0;
constexpr size_t O1 = (size_t)Bn * Fn * 9;
constexpr size_t O2 = O1 + (size_t)Bn * Fn * 6;
constexpr size_t O3 = O2 + (size_t)Bn * Fn * 1;
constexpr size_t O4 = O3 + (size_t)Bn * Fn * 9;

typedef float floatx4 __attribute__((ext_vector_type(4)));

// 12-byte vertex record — loads as one global_load_dwordx3.
struct V3 { float x, y, z; };

// BLAS-order 3-term dot: c = fma(a2,b2, fma(a1,b1, rn(a0*b0)))
__device__ __forceinline__ float dot3_blas(float a0, float a1, float a2,
                                           float b0, float b1, float b2) {
    return fmaf(a2, b2, fmaf(a1, b1, __fmul_rn(a0, b0)));
}

// Coalesced LDS->global flush with NONTEMPORAL stores: keep the 358 MB write
// stream from evicting the gather tables out of the per-XCD L2.
__device__ __forceinline__ void flush4(float* __restrict__ dst,
                                       const float* __restrict__ src,
                                       int nfloats, int tid) {
    const floatx4* s4 = (const floatx4*)src;
    floatx4* d4 = (floatx4*)dst;
    const int n4 = nfloats >> 2;
    for (int i = tid; i < n4; i += 256)
        __builtin_nontemporal_store(s4[i], &d4[i]);
}

__global__ __launch_bounds__(256, 8)   // VGPR<=64 -> 8 blocks/CU (LDS 19.25KB)
void render_mesh_kernel(const float* __restrict__ points,    // [B,P,3]
                        const float* __restrict__ tfcolor,   // [B,P,3]
                        const int*   __restrict__ faces,     // [F,3]
                        const float* __restrict__ cam_rot,   // [B,3,3]
                        const float* __restrict__ cam_pos,   // [B,3]
                        const float* __restrict__ cam_proj,  // [3]
                        float* __restrict__ out)
{
    // 19,456 B total -> 8 blocks/CU (LDS-limited), 32 waves/CU.
    __shared__ __align__(16) float s3d[256 * 9];   // phase 1: points3d; phase 2: colors
    __shared__ __align__(16) float s2d[256 * 6];
    __shared__ __align__(16) float snz[256];
    __shared__ __align__(16) float sn1[256 * 3];

    // XCD-aware batch grouping: XCD k serves only batches {k, k+8}.
    const int blid = blockIdx.x;            // 0 .. 16*782-1
    const int xcd  = blid & 7;
    const int s    = blid >> 3;             // 0 .. 2*782-1
    const int b    = xcd + 8 * (s / ChunksPerB);
    const int blockStart = (s % ChunksPerB) * 256;

    const int t = threadIdx.x;
    const int f = blockStart + t;
    const int nvalid = min(256, Fn - blockStart);   // 256 or 64 (tail)

    float col[3][3];   // colors ride in registers through the first flush

    if (f < Fn) {
        const int i0 = faces[f * 3 + 0];
        const int i1 = faces[f * 3 + 1];
        const int i2 = faces[f * 3 + 2];

        const V3* pb = (const V3*)(points  + (size_t)b * Pn * 3);
        const V3* cb = (const V3*)(tfcolor + (size_t)b * Pn * 3);

        // Issue all 6 gathers up front (max memory-level parallelism).
        const V3 p0 = pb[i0], p1 = pb[i1], p2 = pb[i2];
        const V3 c0v = cb[i0], c1v = cb[i1], c2v = cb[i2];

        // Per-batch camera params — uniform across block (scalar loads).
        const float r00 = cam_rot[b * 9 + 0], r01 = cam_rot[b * 9 + 1], r02 = cam_rot[b * 9 + 2];
        const float r10 = cam_rot[b * 9 + 3], r11 = cam_rot[b * 9 + 4], r12 = cam_rot[b * 9 + 5];
        const float r20 = cam_rot[b * 9 + 6], r21 = cam_rot[b * 9 + 7], r22 = cam_rot[b * 9 + 8];
        const float cp0 = cam_pos[b * 3 + 0], cp1 = cam_pos[b * 3 + 1], cp2 = cam_pos[b * 3 + 2];
        const float pj0 = cam_proj[0], pj1 = cam_proj[1], pj2 = cam_proj[2];

        const V3 pv[3] = {p0, p1, p2};
        col[0][0] = c0v.x; col[0][1] = c0v.y; col[0][2] = c0v.z;
        col[1][0] = c1v.x; col[1][1] = c1v.y; col[1][2] = c1v.z;
        col[2][0] = c2v.x; col[2][1] = c2v.y; col[2][2] = c2v.z;

        float px[3][3];
#pragma unroll
        for (int v = 0; v < 3; ++v) {
            const float dx = __fsub_rn(pv[v].x, cp0);
            const float dy = __fsub_rn(pv[v].y, cp1);
            const float dz = __fsub_rn(pv[v].z, cp2);
            const float tx = dot3_blas(dx, dy, dz, r00, r01, r02);
            const float ty = dot3_blas(dx, dy, dz, r10, r11, r12);
            const float tz = dot3_blas(dx, dy, dz, r20, r21, r22);
            px[v][0] = tx; px[v][1] = ty; px[v][2] = tz;
            s3d[t * 9 + v * 3 + 0] = tx;
            s3d[t * 9 + v * 3 + 1] = ty;
            s3d[t * 9 + v * 3 + 2] = tz;
            const float zv = __fmul_rn(tz, pj2);
            s2d[t * 6 + v * 2 + 0] = __fdiv_rn(__fmul_rn(tx, pj0), zv);
            s2d[t * 6 + v * 2 + 1] = __fdiv_rn(__fmul_rn(ty, pj1), zv);
        }

        // normal = cross(p1-p0, p2-p0)
        const float e1x = px[1][0] - px[0][0], e1y = px[1][1] - px[0][1], e1z = px[1][2] - px[0][2];
        const float e2x = px[2][0] - px[0][0], e2y = px[2][1] - px[0][1], e2z = px[2][2] - px[0][2];
        const float nx = e1y * e2z - e1z * e2y;
        const float ny = e1z * e2x - e1x * e2z;
        const float nz = e1x * e2y - e1y * e2x;
        const float len = sqrtf(nx * nx + ny * ny + nz * nz);
        const float inv = 1.0f / (len + 1e-15f);

        snz[t] = nz;
        sn1[t * 3 + 0] = nx * inv;
        sn1[t * 3 + 1] = ny * inv;
        sn1[t * 3 + 2] = nz * inv;
    }

    __syncthreads();

    const size_t bf0 = (size_t)b * Fn + blockStart;
    // Phase 1 flush: everything except colors.
    flush4(out + O0 + bf0 * 9, s3d, nvalid * 9, t);
    flush4(out + O1 + bf0 * 6, s2d, nvalid * 6, t);
    flush4(out + O2 + bf0 * 1, snz, nvalid * 1, t);
    flush4(out + O4 + bf0 * 3, sn1, nvalid * 3, t);

    __syncthreads();

    // Phase 2: re-stage colors into the (flushed) s3d buffer, flush.
    if (f < Fn) {
#pragma unroll
        for (int v = 0; v < 3; ++v) {
            s3d[t * 9 + v * 3 + 0] = col[v][0];
            s3d[t * 9 + v * 3 + 1] = col[v][1];
            s3d[t * 9 + v * 3 + 2] = col[v][2];
        }
    }
    __syncthreads();
    flush4(out + O3 + bf0 * 9, s3d, nvalid * 9, t);
}

extern "C" void kernel_launch(void* const* d_in, const int* in_sizes, int n_in,
                              void* d_out, int out_size, void* d_ws, size_t ws_size,
                              hipStream_t stream) {
    const float* points   = (const float*)d_in[0];
    const float* tfcolor  = (const float*)d_in[1];
    const int*   faces    = (const int*)d_in[2];
    const float* cam_rot  = (const float*)d_in[3];
    const float* cam_pos  = (const float*)d_in[4];
    const float* cam_proj = (const float*)d_in[5];
    float* out = (float*)d_out;

    dim3 block(256);
    dim3 grid(Bn * ChunksPerB);   // 12512 blocks, 1-D, XCD-swizzled in-kernel
    render_mesh_kernel<<<grid, block, 0, stream>>>(points, tfcolor, faces,
                                                   cam_rot, cam_pos, cam_proj, out);
}